// Round 8
// baseline (1833.368 us; speedup 1.0000x reference)
//
#include <hip/hip_runtime.h>
#include <hip/hip_bf16.h>

#define N_NODES 50000
#define N_EDGES 800000
#define N_GRAPHS 32
#define NODE_DIM 128
#define HIDDEN 256
#define N_LAYERS 3

typedef __attribute__((ext_vector_type(8))) short bh8;   // 8 bf16 (4 VGPRs)
typedef __attribute__((ext_vector_type(4))) short bh4;   // 4 bf16 (8B)
typedef __attribute__((ext_vector_type(4))) float f32x4; // MFMA acc

#define MP 264  // M/H tile pitch (bf16)
#define EP 68   // S_t pitch (fp32, [c][e] layout)
#define SCAN_BS 512
#define OB2 32  // out_stage2 blocks
#define NB_EDGE 512        // persistent edge blocks (2/CU)
#define NTILES (N_EDGES / 64)

// swish via hw rcp (avoids full-precision fp32 divide sequence)
__device__ __forceinline__ float swish_f(float v) {
    return v * __builtin_amdgcn_rcpf(1.0f + __expf(-v));
}

// round-half-up bf16
__device__ __forceinline__ short f2bf(float f) {
    union { float f; unsigned u; } v;
    v.f = f;
    return (short)((v.u + 0x8000u) >> 16);
}

// async global->LDS 16B: per-lane global src, wave-uniform LDS base + lane*16
__device__ __forceinline__ void glds16(void* lds, const void* g) {
    __builtin_amdgcn_global_load_lds(
        (const __attribute__((address_space(1))) unsigned int*)g,
        (__attribute__((address_space(3))) unsigned int*)lds, 16, 0, 0);
}

// d2[e] = |pos[dst] - pos[src] + shift @ lattice[batch[src]]|^2
__global__ void prep_kernel(const float* __restrict__ pos, const float* __restrict__ shift,
                            const float* __restrict__ lattice, const int* __restrict__ eidx,
                            const int* __restrict__ batch, float* __restrict__ d2) {
    int e = blockIdx.x * blockDim.x + threadIdx.x;
    if (e >= N_EDGES) return;
    int s = eidx[e];
    int d = eidx[N_EDGES + e];
    int b = batch[s];
    const float* lat = lattice + b * 9;
    float s0 = shift[e * 3 + 0], s1 = shift[e * 3 + 1], s2 = shift[e * 3 + 2];
    float acc = 0.f;
#pragma unroll
    for (int j = 0; j < 3; j++) {
        float v = pos[d * 3 + j] - pos[s * 3 + j] + s0 * lat[j] + s1 * lat[3 + j] + s2 * lat[6 + j];
        acc += v * v;
    }
    d2[e] = acc;
}

// x[n][c] = embed[z[n]][c]; also bf16 mirror
__global__ void embed_kernel(const float* __restrict__ emb, const int* __restrict__ z,
                             float* __restrict__ x, short* __restrict__ xb) {
    int i = blockIdx.x * blockDim.x + threadIdx.x;
    int n = i >> 7, c = i & 127;
    float v = emb[z[n] * 128 + c];
    x[i] = v;
    xb[i] = f2bf(v);
}

// out[l][h][k] = bf16(in[l][k][h]) for k<K_in else 0
__global__ void cvt_wT_kernel(const float* __restrict__ in, short* __restrict__ out,
                              int K_in, int H, int K_pad, int total) {
    int i = blockIdx.x * blockDim.x + threadIdx.x;
    if (i >= total) return;
    int k = i % K_pad;
    int t = i / K_pad;
    int h = t % H;
    int l = t / H;
    out[i] = (k < K_in) ? f2bf(in[((size_t)l * K_in + k) * H + h]) : (short)0;
}

// ---- CSR counting-sort build ----
__global__ void hist_kernel(const int* __restrict__ eidx, int* __restrict__ deg) {
    int e = blockIdx.x * blockDim.x + threadIdx.x;
    if (e >= N_EDGES) return;
    atomicAdd(&deg[eidx[N_EDGES + e]], 1);
}

__global__ void scan1_kernel(const int* __restrict__ deg, int* __restrict__ sc,
                             int* __restrict__ bsum, int n) {
    __shared__ int s[SCAN_BS];
    int i = blockIdx.x * SCAN_BS + threadIdx.x;
    int v = (i < n) ? deg[i] : 0;
    s[threadIdx.x] = v;
    __syncthreads();
    for (int off = 1; off < SCAN_BS; off <<= 1) {
        int t = (threadIdx.x >= off) ? s[threadIdx.x - off] : 0;
        __syncthreads();
        s[threadIdx.x] += t;
        __syncthreads();
    }
    if (i < n) sc[i] = s[threadIdx.x];
    if (threadIdx.x == SCAN_BS - 1) bsum[blockIdx.x] = s[SCAN_BS - 1];
}

__global__ void scan2_kernel(int* __restrict__ bsum, int nb) {
    __shared__ int s[128];
    int v = (threadIdx.x < nb) ? bsum[threadIdx.x] : 0;
    s[threadIdx.x] = v;
    __syncthreads();
    for (int off = 1; off < 128; off <<= 1) {
        int t = (threadIdx.x >= off) ? s[threadIdx.x - off] : 0;
        __syncthreads();
        s[threadIdx.x] += t;
        __syncthreads();
    }
    if (threadIdx.x < nb) bsum[threadIdx.x] = s[threadIdx.x];
}

__global__ void scan3_kernel(const int* __restrict__ sc, const int* __restrict__ deg,
                             const int* __restrict__ bsum, int* __restrict__ rowptr,
                             int n, int total) {
    int i = blockIdx.x * SCAN_BS + threadIdx.x;
    if (i > n) return;
    if (i == n) { rowptr[n] = total; return; }
    int off = (blockIdx.x > 0) ? bsum[blockIdx.x - 1] : 0;
    rowptr[i] = sc[i] - deg[i] + off;
}

__global__ void fill_kernel(const int* __restrict__ eidx, const int* __restrict__ rowptr,
                            int* __restrict__ fillc, int* __restrict__ esorted) {
    int e = blockIdx.x * blockDim.x + threadIdx.x;
    if (e >= N_EDGES) return;
    int d = eidx[N_EDGES + e];
    int p = rowptr[d] + atomicAdd(&fillc[d], 1);
    esorted[p] = e;
}

// ---------------- Edge MLP: persistent, async-staged, INTERLEAVED tiles ----------------
// Block b processes tiles b, b+NB, b+2NB... -> concurrent blocks work on consecutive
// tiles (moving-window L2 locality, like the r6 dispatch order) while each block
// pipelines its next tile's gather via global_load_lds behind GEMM2+reduction.
// A: chunked layout [wave w][group i:0..8][512 shorts], lane-contiguous per glds instr.
__global__ __launch_bounds__(256, 2) void edge_mlp_mfma(
    const short* __restrict__ xb, const float* __restrict__ d2,
    const int* __restrict__ eidx, const int* __restrict__ esorted,
    const short* __restrict__ W1T,  // [256][288] bf16
    const float* __restrict__ b1,
    const short* __restrict__ W2T,  // [128][256] bf16
    const float* __restrict__ b2,
    float* __restrict__ agg) {
    __shared__ __align__(16) short A[4 * 9 * 512];   // 36,864 B
    __shared__ __align__(16) short Mbuf[17408];      // 34,816 B (M / S_t alias)
    __shared__ int s_dst[2][64];
    short* Mt = Mbuf;
    float* St = (float*)Mbuf;
    const int tid = threadIdx.x;
    const int wv = tid >> 6;
    const int ln = tid & 63;
    const int lr = ln & 15;
    const int lq = ln >> 4;

    const int t0 = blockIdx.x;
    if (t0 >= NTILES) return;

    // ---- prologue: stage tile t0 ----
    {
        int e0 = t0 * 64;
        int ge = esorted[e0 + wv * 16 + (ln >> 2)];
        int sI = eidx[ge];
        int dI = eidx[N_EDGES + ge];
        const short* xd = xb + (size_t)dI * 128;
        const short* xs = xb + (size_t)sI * 128;
        int co = (ln & 3) * 8;
        short* ldsw = A + wv * 4608;
#pragma unroll
        for (int i = 0; i < 4; i++) glds16(ldsw + i * 512 + ln * 8, xd + i * 32 + co);
#pragma unroll
        for (int i = 0; i < 4; i++) glds16(ldsw + (4 + i) * 512 + ln * 8, xs + i * 32 + co);
        int el2 = tid >> 2, j = tid & 3;
        int ge2 = esorted[e0 + el2];
        short tl[8] = {0, 0, 0, 0, 0, 0, 0, 0};
        if (j == 0) {
            s_dst[0][el2] = eidx[N_EDGES + ge2];
            tl[0] = f2bf(d2[ge2]);
        }
        *(int4*)(A + (el2 >> 4) * 4608 + 4096 + (el2 & 15) * 32 + j * 8) = *(int4*)tl;
    }

    int it = 0;
    for (int t = t0; t < NTILES; t += NB_EDGE, ++it) {
        __syncthreads();   // A(t) staged (drains glds), S_t(prev) consumed

        // prefetch next tile's indices (resolve during GEMM1)
        const int tn = t + NB_EDGE;
        const bool haveN = (tn < NTILES);
        int sN = 0, dN = 0, dstN = 0;
        float d2N = 0.f;
        if (haveN) {
            int e0n = tn * 64;
            int geW = esorted[e0n + wv * 16 + (ln >> 2)];
            sN = eidx[geW];
            dN = eidx[N_EDGES + geW];
            int ge2 = esorted[e0n + (tid >> 2)];
            if ((tid & 3) == 0) {
                dstN = eidx[N_EDGES + ge2];
                d2N = d2[ge2];
            }
        }

        // ---- GEMM1 (reads chunked A) + swish -> mv regs ----
        bh4 mv[4][4];
        {
            f32x4 acc[4][4];
#pragma unroll
            for (int a = 0; a < 4; a++)
#pragma unroll
                for (int b = 0; b < 4; b++) acc[a][b] = (f32x4)(0.f);

            const short* a_base = W1T + (size_t)(wv * 64 + lr) * 288 + lq * 8;
            for (int ks = 0; ks < 288; ks += 32) {
                bh8 af[4], bf4[4];
#pragma unroll
                for (int mt = 0; mt < 4; mt++) af[mt] = *(const bh8*)(a_base + mt * 16 * 288 + ks);
#pragma unroll
                for (int nt = 0; nt < 4; nt++)
                    bf4[nt] = *(const bh8*)(A + nt * 4608 + (ks >> 5) * 512 + lr * 32 + lq * 8);
#pragma unroll
                for (int mt = 0; mt < 4; mt++)
#pragma unroll
                    for (int nt = 0; nt < 4; nt++)
                        acc[mt][nt] = __builtin_amdgcn_mfma_f32_16x16x32_bf16(
                            af[mt], bf4[nt], acc[mt][nt], 0, 0, 0);
            }
#pragma unroll
            for (int mt = 0; mt < 4; mt++) {
                int h0 = wv * 64 + mt * 16 + lq * 4;
                float4 bb = *(const float4*)(b1 + h0);
#pragma unroll
                for (int nt = 0; nt < 4; nt++) {
                    mv[mt][nt][0] = f2bf(swish_f(acc[mt][nt][0] + bb.x));
                    mv[mt][nt][1] = f2bf(swish_f(acc[mt][nt][1] + bb.y));
                    mv[mt][nt][2] = f2bf(swish_f(acc[mt][nt][2] + bb.z));
                    mv[mt][nt][3] = f2bf(swish_f(acc[mt][nt][3] + bb.w));
                }
            }
        }
        __syncthreads();   // all waves done reading A(t) -> A free

        // ---- async-stage tile t+NB into A (flies behind GEMM2/reduction) ----
        if (haveN) {
            const short* xd = xb + (size_t)dN * 128;
            const short* xs = xb + (size_t)sN * 128;
            int co = (ln & 3) * 8;
            short* ldsw = A + wv * 4608;
#pragma unroll
            for (int i = 0; i < 4; i++) glds16(ldsw + i * 512 + ln * 8, xd + i * 32 + co);
#pragma unroll
            for (int i = 0; i < 4; i++) glds16(ldsw + (4 + i) * 512 + ln * 8, xs + i * 32 + co);
            int el2 = tid >> 2, j = tid & 3;
            short tl[8] = {0, 0, 0, 0, 0, 0, 0, 0};
            if (j == 0) {
                s_dst[(it + 1) & 1][el2] = dstN;
                tl[0] = f2bf(d2N);
            }
            *(int4*)(A + (el2 >> 4) * 4608 + 4096 + (el2 & 15) * 32 + j * 8) = *(int4*)tl;
        }

        // ---- write M ----
#pragma unroll
        for (int mt = 0; mt < 4; mt++) {
            int h0 = wv * 64 + mt * 16 + lq * 4;
#pragma unroll
            for (int nt = 0; nt < 4; nt++) {
                int e = nt * 16 + lr;
                *(bh4*)(Mt + e * MP + h0) = mv[mt][nt];
            }
        }
        __syncthreads();   // M ready

        // ---- GEMM2 (reads M) -> sv regs ----
        float4 sv[2][4];
        {
            f32x4 acc[2][4];
#pragma unroll
            for (int a = 0; a < 2; a++)
#pragma unroll
                for (int b = 0; b < 4; b++) acc[a][b] = (f32x4)(0.f);

            const short* a_base = W2T + (size_t)(wv * 32 + lr) * 256 + lq * 8;
            for (int ks = 0; ks < 256; ks += 32) {
                bh8 af[2], bf4[4];
#pragma unroll
                for (int mt = 0; mt < 2; mt++) af[mt] = *(const bh8*)(a_base + mt * 16 * 256 + ks);
#pragma unroll
                for (int nt = 0; nt < 4; nt++)
                    bf4[nt] = *(const bh8*)(Mt + (nt * 16 + lr) * MP + ks + lq * 8);
#pragma unroll
                for (int mt = 0; mt < 2; mt++)
#pragma unroll
                    for (int nt = 0; nt < 4; nt++)
                        acc[mt][nt] = __builtin_amdgcn_mfma_f32_16x16x32_bf16(
                            af[mt], bf4[nt], acc[mt][nt], 0, 0, 0);
            }
#pragma unroll
            for (int mt = 0; mt < 2; mt++) {
                int c0 = wv * 32 + mt * 16 + lq * 4;
                float4 bb = *(const float4*)(b2 + c0);
#pragma unroll
                for (int nt = 0; nt < 4; nt++) {
                    sv[mt][nt].x = swish_f(acc[mt][nt][0] + bb.x);
                    sv[mt][nt].y = swish_f(acc[mt][nt][1] + bb.y);
                    sv[mt][nt].z = swish_f(acc[mt][nt][2] + bb.z);
                    sv[mt][nt].w = swish_f(acc[mt][nt][3] + bb.w);
                }
            }
        }
        __syncthreads();   // M dead -> buffer becomes S_t

        // ---- write S_t transposed [c][e] ----
#pragma unroll
        for (int mt = 0; mt < 2; mt++) {
            int c0 = wv * 32 + mt * 16 + lq * 4;
#pragma unroll
            for (int nt = 0; nt < 4; nt++) {
                int e = nt * 16 + lr;
                St[(c0 + 0) * EP + e] = sv[mt][nt].x;
                St[(c0 + 1) * EP + e] = sv[mt][nt].y;
                St[(c0 + 2) * EP + e] = sv[mt][nt].z;
                St[(c0 + 3) * EP + e] = sv[mt][nt].w;
            }
        }
        __syncthreads();   // S_t ready

        // ---- segmented reduction over sorted dst ----
        {
            const int c = tid & 127;
            const int half = tid >> 7;
            const int eb = half * 32;
            const int* sd = s_dst[it & 1];
            float v[32];
            const float* row = St + c * EP + eb;
#pragma unroll
            for (int q = 0; q < 8; q++) *(float4*)&v[q * 4] = *(const float4*)&row[q * 4];
            int cur = sd[eb];
            float acc = v[0];
#pragma unroll
            for (int i = 1; i < 32; i++) {
                int dn = sd[eb + i];
                if (dn != cur) {
                    atomicAdd(agg + (size_t)cur * 128 + c, acc);
                    acc = v[i];
                    cur = dn;
                } else {
                    acc += v[i];
                }
            }
            atomicAdd(agg + (size_t)cur * 128 + c, acc);
        }
    }
}

// ---------------- Node MLP (MFMA, single LDS buffer, 4 blocks/CU) ----------------
__global__ __launch_bounds__(256, 4) void node_mlp_mfma(
    float* __restrict__ x, short* __restrict__ xb, const float* __restrict__ agg,
    const short* __restrict__ W1T, const float* __restrict__ b1,
    const short* __restrict__ W2T, const float* __restrict__ b2) {
    __shared__ __align__(16) short X[64 * MP];
    const int tid = threadIdx.x;
    const int n0 = blockIdx.x * 64;
    const int wv = tid >> 6;
    const int ln = tid & 63;
    const int lr = ln & 15;
    const int lq = ln >> 4;

    {
        int row = tid >> 2, p = tid & 3;
        int gn = n0 + row;
        if (gn < N_NODES) {
            const int4* xp = (const int4*)(xb + (size_t)gn * 128);
#pragma unroll
            for (int q = 0; q < 4; q++) {
                int c = p * 4 + q;
                *(int4*)(X + row * MP + c * 8) = xp[c];
            }
            const float4* ap = (const float4*)(agg + (size_t)gn * 128);
#pragma unroll
            for (int q = 0; q < 4; q++) {
                float4 f0 = ap[p * 8 + q * 2];
                float4 f1 = ap[p * 8 + q * 2 + 1];
                bh8 s;
                s[0] = f2bf(f0.x); s[1] = f2bf(f0.y); s[2] = f2bf(f0.z); s[3] = f2bf(f0.w);
                s[4] = f2bf(f1.x); s[5] = f2bf(f1.y); s[6] = f2bf(f1.z); s[7] = f2bf(f1.w);
                *(bh8*)(X + row * MP + 128 + p * 32 + q * 8) = s;
            }
        } else {
            int4 z4 = make_int4(0, 0, 0, 0);
#pragma unroll
            for (int q = 0; q < 8; q++) *(int4*)(X + row * MP + (p * 8 + q) * 8) = z4;
        }
    }
    __syncthreads();

    bh4 hv[4][4];
    {
        f32x4 acc[4][4];
#pragma unroll
        for (int a = 0; a < 4; a++)
#pragma unroll
            for (int b = 0; b < 4; b++) acc[a][b] = (f32x4)(0.f);

        const short* a_base = W1T + (size_t)(wv * 64 + lr) * 256 + lq * 8;
        for (int ks = 0; ks < 256; ks += 32) {
            bh8 af[4], bf4[4];
#pragma unroll
            for (int mt = 0; mt < 4; mt++) af[mt] = *(const bh8*)(a_base + mt * 16 * 256 + ks);
#pragma unroll
            for (int nt = 0; nt < 4; nt++)
                bf4[nt] = *(const bh8*)(X + (nt * 16 + lr) * MP + ks + lq * 8);
#pragma unroll
            for (int mt = 0; mt < 4; mt++)
#pragma unroll
                for (int nt = 0; nt < 4; nt++)
                    acc[mt][nt] = __builtin_amdgcn_mfma_f32_16x16x32_bf16(af[mt], bf4[nt],
                                                                          acc[mt][nt], 0, 0, 0);
        }
#pragma unroll
        for (int mt = 0; mt < 4; mt++) {
            int h0 = wv * 64 + mt * 16 + lq * 4;
            float4 bb = *(const float4*)(b1 + h0);
#pragma unroll
            for (int nt = 0; nt < 4; nt++) {
                hv[mt][nt][0] = f2bf(swish_f(acc[mt][nt][0] + bb.x));
                hv[mt][nt][1] = f2bf(swish_f(acc[mt][nt][1] + bb.y));
                hv[mt][nt][2] = f2bf(swish_f(acc[mt][nt][2] + bb.z));
                hv[mt][nt][3] = f2bf(swish_f(acc[mt][nt][3] + bb.w));
            }
        }
    }
    __syncthreads();

#pragma unroll
    for (int mt = 0; mt < 4; mt++) {
        int h0 = wv * 64 + mt * 16 + lq * 4;
#pragma unroll
        for (int nt = 0; nt < 4; nt++) {
            int e = nt * 16 + lr;
            *(bh4*)(X + e * MP + h0) = hv[mt][nt];
        }
    }
    __syncthreads();

    {
        f32x4 acc[2][4];
#pragma unroll
        for (int a = 0; a < 2; a++)
#pragma unroll
            for (int b = 0; b < 4; b++) acc[a][b] = (f32x4)(0.f);

        const short* a_base = W2T + (size_t)(wv * 32 + lr) * 256 + lq * 8;
        for (int ks = 0; ks < 256; ks += 32) {
            bh8 af[2], bf4[4];
#pragma unroll
            for (int mt = 0; mt < 2; mt++) af[mt] = *(const bh8*)(a_base + mt * 16 * 256 + ks);
#pragma unroll
            for (int nt = 0; nt < 4; nt++)
                bf4[nt] = *(const bh8*)(X + (nt * 16 + lr) * MP + ks + lq * 8);
#pragma unroll
            for (int mt = 0; mt < 2; mt++)
#pragma unroll
                for (int nt = 0; nt < 4; nt++)
                    acc[mt][nt] = __builtin_amdgcn_mfma_f32_16x16x32_bf16(af[mt], bf4[nt],
                                                                          acc[mt][nt], 0, 0, 0);
        }
#pragma unroll
        for (int mt = 0; mt < 2; mt++) {
            int c0 = wv * 32 + mt * 16 + lq * 4;
            float4 bb = *(const float4*)(b2 + c0);
#pragma unroll
            for (int nt = 0; nt < 4; nt++) {
                int nl = nt * 16 + lr;
                int gn = n0 + nl;
                if (gn < N_NODES) {
                    float4 xv = *(const float4*)(x + (size_t)gn * 128 + c0);
                    float4 nv;
                    nv.x = xv.x + acc[mt][nt][0] + bb.x;
                    nv.y = xv.y + acc[mt][nt][1] + bb.y;
                    nv.z = xv.z + acc[mt][nt][2] + bb.z;
                    nv.w = xv.w + acc[mt][nt][3] + bb.w;
                    *(float4*)(x + (size_t)gn * 128 + c0) = nv;
                    bh4 pk;
                    pk[0] = f2bf(nv.x); pk[1] = f2bf(nv.y); pk[2] = f2bf(nv.z); pk[3] = f2bf(nv.w);
                    *(bh4*)(xb + (size_t)gn * 128 + c0) = pk;
                }
            }
        }
    }
}

// ---------------- Output head, atomic-free 3-stage ----------------
__global__ __launch_bounds__(256, 4) void out_stage1(
    const float* __restrict__ x, const float* __restrict__ w1, const float* __restrict__ b1,
    const float* __restrict__ w2, const float* __restrict__ b2, float* __restrict__ sval) {
    __shared__ float xr[32][128];
    __shared__ float red[4][32];
    const int tid = threadIdx.x;
    const int n0 = blockIdx.x * 32;

    {
        const float4* xs = (const float4*)(x + (size_t)n0 * 128);
        if (n0 + 32 <= N_NODES) {
#pragma unroll
            for (int q = 0; q < 4; q++) {
                int i = tid + q * 256;
                ((float4*)xr)[i] = xs[i];
            }
        } else {
#pragma unroll
            for (int q = 0; q < 4; q++) {
                int i = tid + q * 256;
                int nn = i >> 5;
                ((float4*)xr)[i] = (n0 + nn < N_NODES) ? xs[i] : make_float4(0.f, 0.f, 0.f, 0.f);
            }
        }
    }
    __syncthreads();

    float acc[32];
#pragma unroll
    for (int nn = 0; nn < 32; nn++) acc[nn] = 0.f;

    for (int k = 0; k < 128; k += 4) {
        float w_[4];
#pragma unroll
        for (int kk = 0; kk < 4; kk++) w_[kk] = w1[(size_t)(k + kk) * 256 + tid];
#pragma unroll
        for (int nn = 0; nn < 32; nn++) {
            float4 xv = *(const float4*)&xr[nn][k];
            acc[nn] += xv.x * w_[0] + xv.y * w_[1] + xv.z * w_[2] + xv.w * w_[3];
        }
    }

    const float bb = b1[tid];
    const float wc = w2[tid];
    const int lane = tid & 63, wvi = tid >> 6;
#pragma unroll
    for (int nn = 0; nn < 32; nn++) {
        float v = swish_f(acc[nn] + bb) * wc;
#pragma unroll
        for (int off = 32; off > 0; off >>= 1) v += __shfl_down(v, off, 64);
        if (lane == 0) red[wvi][nn] = v;
    }
    __syncthreads();
    if (tid < 32) {
        int gn = n0 + tid;
        if (gn < N_NODES)
            sval[gn] = red[0][tid] + red[1][tid] + red[2][tid] + red[3][tid] + b2[0];
    }
}

__global__ void out_stage2(const float* __restrict__ sval, const int* __restrict__ batch,
                           float* __restrict__ partial) {
    __shared__ float part[N_GRAPHS];
    const int tid = threadIdx.x;
    if (tid < N_GRAPHS) part[tid] = 0.f;
    __syncthreads();
    const int per_block = (N_NODES + OB2 - 1) / OB2;
    const int start = blockIdx.x * per_block;
    const int end = min(start + per_block, N_NODES);
    const int per_thread = (per_block + 255) / 256;
    int s = start + tid * per_thread;
    int e = min(s + per_thread, end);
    if (s < e) {
        int g = batch[s];
        float a = sval[s];
        for (int n = s + 1; n < e; n++) {
            int gg = batch[n];
            float v = sval[n];
            if (gg != g) {
                atomicAdd(&part[g], a);
                a = v;
                g = gg;
            } else {
                a += v;
            }
        }
        atomicAdd(&part[g], a);
    }
    __syncthreads();
    if (tid < N_GRAPHS) partial[blockIdx.x * N_GRAPHS + tid] = part[tid];
}

__global__ void out_stage3(const float* __restrict__ partial, float* __restrict__ out) {
    int g = threadIdx.x;
    if (g >= N_GRAPHS) return;
    float s = 0.f;
    for (int b = 0; b < OB2; b++) s += partial[b * N_GRAPHS + g];
    out[g] = s;
}

extern "C" void kernel_launch(void* const* d_in, const int* in_sizes, int n_in,
                              void* d_out, int out_size, void* d_ws, size_t ws_size,
                              hipStream_t stream) {
    const float* positions = (const float*)d_in[0];
    const float* edge_shift = (const float*)d_in[1];
    const float* lattice = (const float*)d_in[2];
    const int* atomic_numbers = (const int*)d_in[3];
    const int* edge_index = (const int*)d_in[4];
    const int* batch = (const int*)d_in[5];
    const float* embed_w = (const float*)d_in[6];
    const float* edge_w1 = (const float*)d_in[7];
    const float* edge_b1 = (const float*)d_in[8];
    const float* edge_w2 = (const float*)d_in[9];
    const float* edge_b2 = (const float*)d_in[10];
    const float* node_w1 = (const float*)d_in[11];
    const float* node_b1 = (const float*)d_in[12];
    const float* node_w2 = (const float*)d_in[13];
    const float* node_b2 = (const float*)d_in[14];
    const float* out_w1 = (const float*)d_in[15];
    const float* out_b1 = (const float*)d_in[16];
    const float* out_w2 = (const float*)d_in[17];
    const float* out_b2 = (const float*)d_in[18];

    // workspace layout
    float* ws = (float*)d_ws;
    float* x = ws;                               // N*128 f32
    float* agg = x + (size_t)N_NODES * 128;      // N*128 f32
    float* d2 = agg + (size_t)N_NODES * 128;     // E f32
    short* xb = (short*)(d2 + N_EDGES);          // N*128 bf16
    short* eW1T = xb + (size_t)N_NODES * 128;    // 3*256*288
    short* eW2T = eW1T + 3 * 256 * 288;          // 3*128*256
    short* nW1T = eW2T + 3 * 128 * 256;          // 3*256*256
    short* nW2T = nW1T + 3 * 256 * 256;          // 3*128*256
    int* deg = (int*)(nW2T + 3 * 128 * 256);     // N
    int* fillc = deg + N_NODES;                  // N
    int* sc = fillc + N_NODES;                   // N
    int* bsum = sc + N_NODES;                    // 128
    int* esorted = bsum + 128;                   // E
    int* rowptr = esorted + N_EDGES;             // N+1
    float* sval = (float*)(rowptr + N_NODES + 1);  // N
    float* partial = sval + N_NODES;               // OB2*N_GRAPHS

    (void)hipMemsetAsync(deg, 0, N_NODES * sizeof(int), stream);
    (void)hipMemsetAsync(fillc, 0, N_NODES * sizeof(int), stream);

    // weight transpose+cvt (tiny)
    {
        int t1 = 3 * 256 * 288;
        cvt_wT_kernel<<<(t1 + 255) / 256, 256, 0, stream>>>(edge_w1, eW1T, 257, 256, 288, t1);
        int t2 = 3 * 128 * 256;
        cvt_wT_kernel<<<(t2 + 255) / 256, 256, 0, stream>>>(edge_w2, eW2T, 256, 128, 256, t2);
        int t3 = 3 * 256 * 256;
        cvt_wT_kernel<<<(t3 + 255) / 256, 256, 0, stream>>>(node_w1, nW1T, 256, 256, 256, t3);
        cvt_wT_kernel<<<(t2 + 255) / 256, 256, 0, stream>>>(node_w2, nW2T, 256, 128, 256, t2);
    }

    prep_kernel<<<(N_EDGES + 255) / 256, 256, 0, stream>>>(positions, edge_shift, lattice,
                                                           edge_index, batch, d2);
    embed_kernel<<<(N_NODES * 128) / 256, 256, 0, stream>>>(embed_w, atomic_numbers, x, xb);

    // CSR counting sort by dst
    {
        int nscan = (N_NODES + SCAN_BS - 1) / SCAN_BS;
        hist_kernel<<<(N_EDGES + 255) / 256, 256, 0, stream>>>(edge_index, deg);
        scan1_kernel<<<nscan, SCAN_BS, 0, stream>>>(deg, sc, bsum, N_NODES);
        scan2_kernel<<<1, 128, 0, stream>>>(bsum, nscan);
        scan3_kernel<<<(N_NODES + SCAN_BS) / SCAN_BS + 1, SCAN_BS, 0, stream>>>(
            sc, deg, bsum, rowptr, N_NODES, N_EDGES);
        fill_kernel<<<(N_EDGES + 255) / 256, 256, 0, stream>>>(edge_index, rowptr, fillc,
                                                               esorted);
    }

    for (int l = 0; l < N_LAYERS; l++) {
        (void)hipMemsetAsync(agg, 0, (size_t)N_NODES * 128 * sizeof(float), stream);
        edge_mlp_mfma<<<NB_EDGE, 256, 0, stream>>>(
            xb, d2, edge_index, esorted,
            eW1T + (size_t)l * 256 * 288, edge_b1 + (size_t)l * 256,
            eW2T + (size_t)l * 128 * 256, edge_b2 + (size_t)l * 128, agg);
        node_mlp_mfma<<<(N_NODES + 63) / 64, 256, 0, stream>>>(
            x, xb, agg,
            nW1T + (size_t)l * 256 * 256, node_b1 + (size_t)l * 256,
            nW2T + (size_t)l * 128 * 256, node_b2 + (size_t)l * 128);
    }
    out_stage1<<<(N_NODES + 31) / 32, 256, 0, stream>>>(x, out_w1, out_b1, out_w2, out_b2, sval);
    out_stage2<<<OB2, 256, 0, stream>>>(sval, batch, partial);
    out_stage3<<<1, 64, 0, stream>>>(partial, (float*)d_out);
}

// Round 9
// 1376.744 us; speedup vs baseline: 1.3317x; 1.3317x over previous
//
#include <hip/hip_runtime.h>
#include <hip/hip_bf16.h>

#define N_NODES 50000
#define N_EDGES 800000
#define N_GRAPHS 32
#define NODE_DIM 128
#define HIDDEN 256
#define N_LAYERS 3

typedef __attribute__((ext_vector_type(8))) short bh8;   // 8 bf16 (4 VGPRs)
typedef __attribute__((ext_vector_type(4))) short bh4;   // 4 bf16 (8B)
typedef __attribute__((ext_vector_type(4))) float f32x4; // MFMA acc

#define MP 264  // M/H tile pitch (bf16)
#define EP 68   // S_t pitch (fp32, [c][e] layout)
#define SCAN_BS 512
#define OB2 32  // out_stage2 blocks

// swish via hw rcp (avoids full-precision fp32 divide sequence)
__device__ __forceinline__ float swish_f(float v) {
    return v * __builtin_amdgcn_rcpf(1.0f + __expf(-v));
}

// round-half-up bf16
__device__ __forceinline__ short f2bf(float f) {
    union { float f; unsigned u; } v;
    v.f = f;
    return (short)((v.u + 0x8000u) >> 16);
}

// d2[e] = |pos[dst] - pos[src] + shift @ lattice[batch[src]]|^2
__global__ void prep_kernel(const float* __restrict__ pos, const float* __restrict__ shift,
                            const float* __restrict__ lattice, const int* __restrict__ eidx,
                            const int* __restrict__ batch, float* __restrict__ d2) {
    int e = blockIdx.x * blockDim.x + threadIdx.x;
    if (e >= N_EDGES) return;
    int s = eidx[e];
    int d = eidx[N_EDGES + e];
    int b = batch[s];
    const float* lat = lattice + b * 9;
    float s0 = shift[e * 3 + 0], s1 = shift[e * 3 + 1], s2 = shift[e * 3 + 2];
    float acc = 0.f;
#pragma unroll
    for (int j = 0; j < 3; j++) {
        float v = pos[d * 3 + j] - pos[s * 3 + j] + s0 * lat[j] + s1 * lat[3 + j] + s2 * lat[6 + j];
        acc += v * v;
    }
    d2[e] = acc;
}

// x[n][c] = embed[z[n]][c]; also bf16 mirror
__global__ void embed_kernel(const float* __restrict__ emb, const int* __restrict__ z,
                             float* __restrict__ x, short* __restrict__ xb) {
    int i = blockIdx.x * blockDim.x + threadIdx.x;
    int n = i >> 7, c = i & 127;
    float v = emb[z[n] * 128 + c];
    x[i] = v;
    xb[i] = f2bf(v);
}

// out[l][h][k] = bf16(in[l][k][h]) for k<K_in else 0
__global__ void cvt_wT_kernel(const float* __restrict__ in, short* __restrict__ out,
                              int K_in, int H, int K_pad, int total) {
    int i = blockIdx.x * blockDim.x + threadIdx.x;
    if (i >= total) return;
    int k = i % K_pad;
    int t = i / K_pad;
    int h = t % H;
    int l = t / H;
    out[i] = (k < K_in) ? f2bf(in[((size_t)l * K_in + k) * H + h]) : (short)0;
}

// ---- CSR counting-sort build ----
__global__ void hist_kernel(const int* __restrict__ eidx, int* __restrict__ deg) {
    int e = blockIdx.x * blockDim.x + threadIdx.x;
    if (e >= N_EDGES) return;
    atomicAdd(&deg[eidx[N_EDGES + e]], 1);
}

__global__ void scan1_kernel(const int* __restrict__ deg, int* __restrict__ sc,
                             int* __restrict__ bsum, int n) {
    __shared__ int s[SCAN_BS];
    int i = blockIdx.x * SCAN_BS + threadIdx.x;
    int v = (i < n) ? deg[i] : 0;
    s[threadIdx.x] = v;
    __syncthreads();
    for (int off = 1; off < SCAN_BS; off <<= 1) {
        int t = (threadIdx.x >= off) ? s[threadIdx.x - off] : 0;
        __syncthreads();
        s[threadIdx.x] += t;
        __syncthreads();
    }
    if (i < n) sc[i] = s[threadIdx.x];
    if (threadIdx.x == SCAN_BS - 1) bsum[blockIdx.x] = s[SCAN_BS - 1];
}

__global__ void scan2_kernel(int* __restrict__ bsum, int nb) {
    __shared__ int s[128];
    int v = (threadIdx.x < nb) ? bsum[threadIdx.x] : 0;
    s[threadIdx.x] = v;
    __syncthreads();
    for (int off = 1; off < 128; off <<= 1) {
        int t = (threadIdx.x >= off) ? s[threadIdx.x - off] : 0;
        __syncthreads();
        s[threadIdx.x] += t;
        __syncthreads();
    }
    if (threadIdx.x < nb) bsum[threadIdx.x] = s[threadIdx.x];
}

__global__ void scan3_kernel(const int* __restrict__ sc, const int* __restrict__ deg,
                             const int* __restrict__ bsum, int* __restrict__ rowptr,
                             int n, int total) {
    int i = blockIdx.x * SCAN_BS + threadIdx.x;
    if (i > n) return;
    if (i == n) { rowptr[n] = total; return; }
    int off = (blockIdx.x > 0) ? bsum[blockIdx.x - 1] : 0;
    rowptr[i] = sc[i] - deg[i] + off;
}

__global__ void fill_kernel(const int* __restrict__ eidx, const int* __restrict__ rowptr,
                            int* __restrict__ fillc, int* __restrict__ esorted) {
    int e = blockIdx.x * blockDim.x + threadIdx.x;
    if (e >= N_EDGES) return;
    int d = eidx[N_EDGES + e];
    int p = rowptr[d] + atomicAdd(&fillc[d], 1);
    esorted[p] = e;
}

// ---------------- Edge MLP (MFMA, dst-sorted, single LDS buffer, chunked A) ----------------
// One 36.9KB buffer X time-shares: A(chunked) -> M [64][MP] -> S_t [128][EP] (fp32).
// A chunked layout: A(e,k) at short index (e>>4)*4608 + (k>>5)*512 + (e&15)*32 + ((k>>3)&3)*8
//  -> GEMM1 fragment reads are lane-contiguous 1024B/wave (bank-conflict-free), and
//     staging writes (lane ln <-> edge ln>>2, col-quad ln&3) are ds_write_b128-contiguous.
__global__ __launch_bounds__(256, 4) void edge_mlp_mfma(
    const short* __restrict__ xb, const float* __restrict__ d2,
    const int* __restrict__ eidx, const int* __restrict__ esorted,
    const short* __restrict__ W1T,  // [256][288] bf16
    const float* __restrict__ b1,
    const short* __restrict__ W2T,  // [128][256] bf16
    const float* __restrict__ b2,
    float* __restrict__ agg) {
    __shared__ __align__(16) short X[4 * 9 * 512];   // 36,864 B
    __shared__ int s_dst[64];
    short* Mt = X;
    float* St = (float*)X;
    const int tid = threadIdx.x;
    const int e0 = blockIdx.x * 64;
    const int wv = tid >> 6;
    const int ln = tid & 63;
    const int lr = ln & 15;
    const int lq = ln >> 4;

    // ---- stage A (chunked, conflict-free ds_write_b128) ----
    {
        int ew = wv * 16 + (ln >> 2);          // edge within tile this lane stages
        int ge = esorted[e0 + ew];
        int sI = eidx[ge];
        int dI = eidx[N_EDGES + ge];
        const int4* xd = (const int4*)(xb + (size_t)dI * 128);
        const int4* xs = (const int4*)(xb + (size_t)sI * 128);
        int cq = ln & 3;                        // 16B-chunk within 32-short group
        short* ldsw = X + wv * 4608;
#pragma unroll
        for (int i = 0; i < 4; i++)
            *(int4*)(ldsw + i * 512 + ln * 8) = xd[i * 4 + cq];
#pragma unroll
        for (int i = 0; i < 4; i++)
            *(int4*)(ldsw + (4 + i) * 512 + ln * 8) = xs[i * 4 + cq];
        // tail group 8: d2 at k=256, zeros 257..287
        int el2 = tid >> 2, j = tid & 3;
        int ge2 = esorted[e0 + el2];
        short tl[8] = {0, 0, 0, 0, 0, 0, 0, 0};
        if (j == 0) {
            s_dst[el2] = eidx[N_EDGES + ge2];
            tl[0] = f2bf(d2[ge2]);
        }
        *(int4*)(X + (el2 >> 4) * 4608 + 8 * 512 + (el2 & 15) * 32 + j * 8) = *(int4*)tl;
    }
    __syncthreads();

    // ---- GEMM1 (reads chunked A) + swish -> mv regs ----
    bh4 mv[4][4];
    {
        f32x4 acc[4][4];
#pragma unroll
        for (int a = 0; a < 4; a++)
#pragma unroll
            for (int b = 0; b < 4; b++) acc[a][b] = (f32x4)(0.f);

        const short* a_base = W1T + (size_t)(wv * 64 + lr) * 288 + lq * 8;
        for (int ks = 0; ks < 288; ks += 32) {
            bh8 af[4], bf4[4];
#pragma unroll
            for (int mt = 0; mt < 4; mt++) af[mt] = *(const bh8*)(a_base + mt * 16 * 288 + ks);
#pragma unroll
            for (int nt = 0; nt < 4; nt++)
                bf4[nt] = *(const bh8*)(X + nt * 4608 + (ks >> 5) * 512 + lr * 32 + lq * 8);
#pragma unroll
            for (int mt = 0; mt < 4; mt++)
#pragma unroll
                for (int nt = 0; nt < 4; nt++)
                    acc[mt][nt] = __builtin_amdgcn_mfma_f32_16x16x32_bf16(
                        af[mt], bf4[nt], acc[mt][nt], 0, 0, 0);
        }
#pragma unroll
        for (int mt = 0; mt < 4; mt++) {
            int h0 = wv * 64 + mt * 16 + lq * 4;
            float4 bb = *(const float4*)(b1 + h0);
#pragma unroll
            for (int nt = 0; nt < 4; nt++) {
                mv[mt][nt][0] = f2bf(swish_f(acc[mt][nt][0] + bb.x));
                mv[mt][nt][1] = f2bf(swish_f(acc[mt][nt][1] + bb.y));
                mv[mt][nt][2] = f2bf(swish_f(acc[mt][nt][2] + bb.z));
                mv[mt][nt][3] = f2bf(swish_f(acc[mt][nt][3] + bb.w));
            }
        }
    }
    __syncthreads();   // everyone done reading A -> buffer becomes M

    // ---- write M ----
#pragma unroll
    for (int mt = 0; mt < 4; mt++) {
        int h0 = wv * 64 + mt * 16 + lq * 4;
#pragma unroll
        for (int nt = 0; nt < 4; nt++) {
            int e = nt * 16 + lr;
            *(bh4*)(Mt + e * MP + h0) = mv[mt][nt];
        }
    }
    __syncthreads();

    // ---- GEMM2 (reads M) + swish -> sv regs ----
    float4 sv[2][4];
    {
        f32x4 acc[2][4];
#pragma unroll
        for (int a = 0; a < 2; a++)
#pragma unroll
            for (int b = 0; b < 4; b++) acc[a][b] = (f32x4)(0.f);

        const short* a_base = W2T + (size_t)(wv * 32 + lr) * 256 + lq * 8;
        for (int ks = 0; ks < 256; ks += 32) {
            bh8 af[2], bf4[4];
#pragma unroll
            for (int mt = 0; mt < 2; mt++) af[mt] = *(const bh8*)(a_base + mt * 16 * 256 + ks);
#pragma unroll
            for (int nt = 0; nt < 4; nt++)
                bf4[nt] = *(const bh8*)(Mt + (nt * 16 + lr) * MP + ks + lq * 8);
#pragma unroll
            for (int mt = 0; mt < 2; mt++)
#pragma unroll
                for (int nt = 0; nt < 4; nt++)
                    acc[mt][nt] = __builtin_amdgcn_mfma_f32_16x16x32_bf16(
                        af[mt], bf4[nt], acc[mt][nt], 0, 0, 0);
        }
#pragma unroll
        for (int mt = 0; mt < 2; mt++) {
            int c0 = wv * 32 + mt * 16 + lq * 4;
            float4 bb = *(const float4*)(b2 + c0);
#pragma unroll
            for (int nt = 0; nt < 4; nt++) {
                sv[mt][nt].x = swish_f(acc[mt][nt][0] + bb.x);
                sv[mt][nt].y = swish_f(acc[mt][nt][1] + bb.y);
                sv[mt][nt].z = swish_f(acc[mt][nt][2] + bb.z);
                sv[mt][nt].w = swish_f(acc[mt][nt][3] + bb.w);
            }
        }
    }
    __syncthreads();   // M dead -> buffer becomes S_t

    // ---- write S_t transposed [c][e] ----
#pragma unroll
    for (int mt = 0; mt < 2; mt++) {
        int c0 = wv * 32 + mt * 16 + lq * 4;
#pragma unroll
        for (int nt = 0; nt < 4; nt++) {
            int e = nt * 16 + lr;
            St[(c0 + 0) * EP + e] = sv[mt][nt].x;
            St[(c0 + 1) * EP + e] = sv[mt][nt].y;
            St[(c0 + 2) * EP + e] = sv[mt][nt].z;
            St[(c0 + 3) * EP + e] = sv[mt][nt].w;
        }
    }
    __syncthreads();

    // ---- segmented reduction: vector-load 32 contiguous values, register scan ----
    {
        const int c = tid & 127;
        const int half = tid >> 7;
        const int eb = half * 32;
        float v[32];
        const float* row = St + c * EP + eb;
#pragma unroll
        for (int q = 0; q < 8; q++) *(float4*)&v[q * 4] = *(const float4*)&row[q * 4];
        int cur = s_dst[eb];
        float acc = v[0];
#pragma unroll
        for (int i = 1; i < 32; i++) {
            int dn = s_dst[eb + i];
            if (dn != cur) {
                atomicAdd(agg + (size_t)cur * 128 + c, acc);
                acc = v[i];
                cur = dn;
            } else {
                acc += v[i];
            }
        }
        atomicAdd(agg + (size_t)cur * 128 + c, acc);
    }
}

// ---------------- Node MLP (MFMA, single LDS buffer, 4 blocks/CU) ----------------
__global__ __launch_bounds__(256, 4) void node_mlp_mfma(
    float* __restrict__ x, short* __restrict__ xb, const float* __restrict__ agg,
    const short* __restrict__ W1T, const float* __restrict__ b1,
    const short* __restrict__ W2T, const float* __restrict__ b2) {
    __shared__ __align__(16) short X[64 * MP];
    const int tid = threadIdx.x;
    const int n0 = blockIdx.x * 64;
    const int wv = tid >> 6;
    const int ln = tid & 63;
    const int lr = ln & 15;
    const int lq = ln >> 4;

    {
        int row = tid >> 2, p = tid & 3;
        int gn = n0 + row;
        if (gn < N_NODES) {
            const int4* xp = (const int4*)(xb + (size_t)gn * 128);
#pragma unroll
            for (int q = 0; q < 4; q++) {
                int c = p * 4 + q;
                *(int4*)(X + row * MP + c * 8) = xp[c];
            }
            const float4* ap = (const float4*)(agg + (size_t)gn * 128);
#pragma unroll
            for (int q = 0; q < 4; q++) {
                float4 f0 = ap[p * 8 + q * 2];
                float4 f1 = ap[p * 8 + q * 2 + 1];
                bh8 s;
                s[0] = f2bf(f0.x); s[1] = f2bf(f0.y); s[2] = f2bf(f0.z); s[3] = f2bf(f0.w);
                s[4] = f2bf(f1.x); s[5] = f2bf(f1.y); s[6] = f2bf(f1.z); s[7] = f2bf(f1.w);
                *(bh8*)(X + row * MP + 128 + p * 32 + q * 8) = s;
            }
        } else {
            int4 z4 = make_int4(0, 0, 0, 0);
#pragma unroll
            for (int q = 0; q < 8; q++) *(int4*)(X + row * MP + (p * 8 + q) * 8) = z4;
        }
    }
    __syncthreads();

    bh4 hv[4][4];
    {
        f32x4 acc[4][4];
#pragma unroll
        for (int a = 0; a < 4; a++)
#pragma unroll
            for (int b = 0; b < 4; b++) acc[a][b] = (f32x4)(0.f);

        const short* a_base = W1T + (size_t)(wv * 64 + lr) * 256 + lq * 8;
        for (int ks = 0; ks < 256; ks += 32) {
            bh8 af[4], bf4[4];
#pragma unroll
            for (int mt = 0; mt < 4; mt++) af[mt] = *(const bh8*)(a_base + mt * 16 * 256 + ks);
#pragma unroll
            for (int nt = 0; nt < 4; nt++)
                bf4[nt] = *(const bh8*)(X + (nt * 16 + lr) * MP + ks + lq * 8);
#pragma unroll
            for (int mt = 0; mt < 4; mt++)
#pragma unroll
                for (int nt = 0; nt < 4; nt++)
                    acc[mt][nt] = __builtin_amdgcn_mfma_f32_16x16x32_bf16(af[mt], bf4[nt],
                                                                          acc[mt][nt], 0, 0, 0);
        }
#pragma unroll
        for (int mt = 0; mt < 4; mt++) {
            int h0 = wv * 64 + mt * 16 + lq * 4;
            float4 bb = *(const float4*)(b1 + h0);
#pragma unroll
            for (int nt = 0; nt < 4; nt++) {
                hv[mt][nt][0] = f2bf(swish_f(acc[mt][nt][0] + bb.x));
                hv[mt][nt][1] = f2bf(swish_f(acc[mt][nt][1] + bb.y));
                hv[mt][nt][2] = f2bf(swish_f(acc[mt][nt][2] + bb.z));
                hv[mt][nt][3] = f2bf(swish_f(acc[mt][nt][3] + bb.w));
            }
        }
    }
    __syncthreads();

#pragma unroll
    for (int mt = 0; mt < 4; mt++) {
        int h0 = wv * 64 + mt * 16 + lq * 4;
#pragma unroll
        for (int nt = 0; nt < 4; nt++) {
            int e = nt * 16 + lr;
            *(bh4*)(X + e * MP + h0) = hv[mt][nt];
        }
    }
    __syncthreads();

    {
        f32x4 acc[2][4];
#pragma unroll
        for (int a = 0; a < 2; a++)
#pragma unroll
            for (int b = 0; b < 4; b++) acc[a][b] = (f32x4)(0.f);

        const short* a_base = W2T + (size_t)(wv * 32 + lr) * 256 + lq * 8;
        for (int ks = 0; ks < 256; ks += 32) {
            bh8 af[2], bf4[4];
#pragma unroll
            for (int mt = 0; mt < 2; mt++) af[mt] = *(const bh8*)(a_base + mt * 16 * 256 + ks);
#pragma unroll
            for (int nt = 0; nt < 4; nt++)
                bf4[nt] = *(const bh8*)(X + (nt * 16 + lr) * MP + ks + lq * 8);
#pragma unroll
            for (int mt = 0; mt < 2; mt++)
#pragma unroll
                for (int nt = 0; nt < 4; nt++)
                    acc[mt][nt] = __builtin_amdgcn_mfma_f32_16x16x32_bf16(af[mt], bf4[nt],
                                                                          acc[mt][nt], 0, 0, 0);
        }
#pragma unroll
        for (int mt = 0; mt < 2; mt++) {
            int c0 = wv * 32 + mt * 16 + lq * 4;
            float4 bb = *(const float4*)(b2 + c0);
#pragma unroll
            for (int nt = 0; nt < 4; nt++) {
                int nl = nt * 16 + lr;
                int gn = n0 + nl;
                if (gn < N_NODES) {
                    float4 xv = *(const float4*)(x + (size_t)gn * 128 + c0);
                    float4 nv;
                    nv.x = xv.x + acc[mt][nt][0] + bb.x;
                    nv.y = xv.y + acc[mt][nt][1] + bb.y;
                    nv.z = xv.z + acc[mt][nt][2] + bb.z;
                    nv.w = xv.w + acc[mt][nt][3] + bb.w;
                    *(float4*)(x + (size_t)gn * 128 + c0) = nv;
                    bh4 pk;
                    pk[0] = f2bf(nv.x); pk[1] = f2bf(nv.y); pk[2] = f2bf(nv.z); pk[3] = f2bf(nv.w);
                    *(bh4*)(xb + (size_t)gn * 128 + c0) = pk;
                }
            }
        }
    }
}

// ---------------- Output head, atomic-free 3-stage ----------------
__global__ __launch_bounds__(256, 4) void out_stage1(
    const float* __restrict__ x, const float* __restrict__ w1, const float* __restrict__ b1,
    const float* __restrict__ w2, const float* __restrict__ b2, float* __restrict__ sval) {
    __shared__ float xr[32][128];
    __shared__ float red[4][32];
    const int tid = threadIdx.x;
    const int n0 = blockIdx.x * 32;

    {
        const float4* xs = (const float4*)(x + (size_t)n0 * 128);
        if (n0 + 32 <= N_NODES) {
#pragma unroll
            for (int q = 0; q < 4; q++) {
                int i = tid + q * 256;
                ((float4*)xr)[i] = xs[i];
            }
        } else {
#pragma unroll
            for (int q = 0; q < 4; q++) {
                int i = tid + q * 256;
                int nn = i >> 5;
                ((float4*)xr)[i] = (n0 + nn < N_NODES) ? xs[i] : make_float4(0.f, 0.f, 0.f, 0.f);
            }
        }
    }
    __syncthreads();

    float acc[32];
#pragma unroll
    for (int nn = 0; nn < 32; nn++) acc[nn] = 0.f;

    for (int k = 0; k < 128; k += 4) {
        float w_[4];
#pragma unroll
        for (int kk = 0; kk < 4; kk++) w_[kk] = w1[(size_t)(k + kk) * 256 + tid];
#pragma unroll
        for (int nn = 0; nn < 32; nn++) {
            float4 xv = *(const float4*)&xr[nn][k];
            acc[nn] += xv.x * w_[0] + xv.y * w_[1] + xv.z * w_[2] + xv.w * w_[3];
        }
    }

    const float bb = b1[tid];
    const float wc = w2[tid];
    const int lane = tid & 63, wvi = tid >> 6;
#pragma unroll
    for (int nn = 0; nn < 32; nn++) {
        float v = swish_f(acc[nn] + bb) * wc;
#pragma unroll
        for (int off = 32; off > 0; off >>= 1) v += __shfl_down(v, off, 64);
        if (lane == 0) red[wvi][nn] = v;
    }
    __syncthreads();
    if (tid < 32) {
        int gn = n0 + tid;
        if (gn < N_NODES)
            sval[gn] = red[0][tid] + red[1][tid] + red[2][tid] + red[3][tid] + b2[0];
    }
}

__global__ void out_stage2(const float* __restrict__ sval, const int* __restrict__ batch,
                           float* __restrict__ partial) {
    __shared__ float part[N_GRAPHS];
    const int tid = threadIdx.x;
    if (tid < N_GRAPHS) part[tid] = 0.f;
    __syncthreads();
    const int per_block = (N_NODES + OB2 - 1) / OB2;
    const int start = blockIdx.x * per_block;
    const int end = min(start + per_block, N_NODES);
    const int per_thread = (per_block + 255) / 256;
    int s = start + tid * per_thread;
    int e = min(s + per_thread, end);
    if (s < e) {
        int g = batch[s];
        float a = sval[s];
        for (int n = s + 1; n < e; n++) {
            int gg = batch[n];
            float v = sval[n];
            if (gg != g) {
                atomicAdd(&part[g], a);
                a = v;
                g = gg;
            } else {
                a += v;
            }
        }
        atomicAdd(&part[g], a);
    }
    __syncthreads();
    if (tid < N_GRAPHS) partial[blockIdx.x * N_GRAPHS + tid] = part[tid];
}

__global__ void out_stage3(const float* __restrict__ partial, float* __restrict__ out) {
    int g = threadIdx.x;
    if (g >= N_GRAPHS) return;
    float s = 0.f;
    for (int b = 0; b < OB2; b++) s += partial[b * N_GRAPHS + g];
    out[g] = s;
}

extern "C" void kernel_launch(void* const* d_in, const int* in_sizes, int n_in,
                              void* d_out, int out_size, void* d_ws, size_t ws_size,
                              hipStream_t stream) {
    const float* positions = (const float*)d_in[0];
    const float* edge_shift = (const float*)d_in[1];
    const float* lattice = (const float*)d_in[2];
    const int* atomic_numbers = (const int*)d_in[3];
    const int* edge_index = (const int*)d_in[4];
    const int* batch = (const int*)d_in[5];
    const float* embed_w = (const float*)d_in[6];
    const float* edge_w1 = (const float*)d_in[7];
    const float* edge_b1 = (const float*)d_in[8];
    const float* edge_w2 = (const float*)d_in[9];
    const float* edge_b2 = (const float*)d_in[10];
    const float* node_w1 = (const float*)d_in[11];
    const float* node_b1 = (const float*)d_in[12];
    const float* node_w2 = (const float*)d_in[13];
    const float* node_b2 = (const float*)d_in[14];
    const float* out_w1 = (const float*)d_in[15];
    const float* out_b1 = (const float*)d_in[16];
    const float* out_w2 = (const float*)d_in[17];
    const float* out_b2 = (const float*)d_in[18];

    // workspace layout
    float* ws = (float*)d_ws;
    float* x = ws;                               // N*128 f32
    float* agg = x + (size_t)N_NODES * 128;      // N*128 f32
    float* d2 = agg + (size_t)N_NODES * 128;     // E f32
    short* xb = (short*)(d2 + N_EDGES);          // N*128 bf16
    short* eW1T = xb + (size_t)N_NODES * 128;    // 3*256*288
    short* eW2T = eW1T + 3 * 256 * 288;          // 3*128*256
    short* nW1T = eW2T + 3 * 128 * 256;          // 3*256*256
    short* nW2T = nW1T + 3 * 256 * 256;          // 3*128*256
    int* deg = (int*)(nW2T + 3 * 128 * 256);     // N
    int* fillc = deg + N_NODES;                  // N
    int* sc = fillc + N_NODES;                   // N
    int* bsum = sc + N_NODES;                    // 128
    int* esorted = bsum + 128;                   // E
    int* rowptr = esorted + N_EDGES;             // N+1
    float* sval = (float*)(rowptr + N_NODES + 1);  // N
    float* partial = sval + N_NODES;               // OB2*N_GRAPHS

    (void)hipMemsetAsync(deg, 0, N_NODES * sizeof(int), stream);
    (void)hipMemsetAsync(fillc, 0, N_NODES * sizeof(int), stream);

    // weight transpose+cvt (tiny)
    {
        int t1 = 3 * 256 * 288;
        cvt_wT_kernel<<<(t1 + 255) / 256, 256, 0, stream>>>(edge_w1, eW1T, 257, 256, 288, t1);
        int t2 = 3 * 128 * 256;
        cvt_wT_kernel<<<(t2 + 255) / 256, 256, 0, stream>>>(edge_w2, eW2T, 256, 128, 256, t2);
        int t3 = 3 * 256 * 256;
        cvt_wT_kernel<<<(t3 + 255) / 256, 256, 0, stream>>>(node_w1, nW1T, 256, 256, 256, t3);
        cvt_wT_kernel<<<(t2 + 255) / 256, 256, 0, stream>>>(node_w2, nW2T, 256, 128, 256, t2);
    }

    prep_kernel<<<(N_EDGES + 255) / 256, 256, 0, stream>>>(positions, edge_shift, lattice,
                                                           edge_index, batch, d2);
    embed_kernel<<<(N_NODES * 128) / 256, 256, 0, stream>>>(embed_w, atomic_numbers, x, xb);

    // CSR counting sort by dst
    {
        int nscan = (N_NODES + SCAN_BS - 1) / SCAN_BS;
        hist_kernel<<<(N_EDGES + 255) / 256, 256, 0, stream>>>(edge_index, deg);
        scan1_kernel<<<nscan, SCAN_BS, 0, stream>>>(deg, sc, bsum, N_NODES);
        scan2_kernel<<<1, 128, 0, stream>>>(bsum, nscan);
        scan3_kernel<<<(N_NODES + SCAN_BS) / SCAN_BS + 1, SCAN_BS, 0, stream>>>(
            sc, deg, bsum, rowptr, N_NODES, N_EDGES);
        fill_kernel<<<(N_EDGES + 255) / 256, 256, 0, stream>>>(edge_index, rowptr, fillc,
                                                               esorted);
    }

    for (int l = 0; l < N_LAYERS; l++) {
        (void)hipMemsetAsync(agg, 0, (size_t)N_NODES * 128 * sizeof(float), stream);
        edge_mlp_mfma<<<N_EDGES / 64, 256, 0, stream>>>(
            xb, d2, edge_index, esorted,
            eW1T + (size_t)l * 256 * 288, edge_b1 + (size_t)l * 256,
            eW2T + (size_t)l * 128 * 256, edge_b2 + (size_t)l * 128, agg);
        node_mlp_mfma<<<(N_NODES + 63) / 64, 256, 0, stream>>>(
            x, xb, agg,
            nW1T + (size_t)l * 256 * 256, node_b1 + (size_t)l * 256,
            nW2T + (size_t)l * 128 * 256, node_b2 + (size_t)l * 128);
    }
    out_stage1<<<(N_NODES + 31) / 32, 256, 0, stream>>>(x, out_w1, out_b1, out_w2, out_b2, sval);
    out_stage2<<<OB2, 256, 0, stream>>>(sval, batch, partial);
    out_stage3<<<1, 64, 0, stream>>>(partial, (float*)d_out);
}